// Round 1
// baseline (538.563 us; speedup 1.0000x reference)
//
#include <hip/hip_runtime.h>

static constexpr int B = 256, L = 2048, T = 17;
#define LOG2E 1.4426950408889634f
#define LN2   0.6931471805599453f

// ---------------------------------------------------------------------------
// Denominator: forward logsumexp scan. One batch per wave (block = 1 wave).
// Log2-domain trick: logsumexp_i(a_i + T_ij) = log2( sum_i 2^a_i * W_ij ),
// W_ij = 2^(T_ij*log2e) precomputed in registers (lane j holds column j).
// Running offset C keeps a_rel[0] == 0 for stability (spread bounded ~±13).
// ---------------------------------------------------------------------------
__global__ __launch_bounds__(64) void crf_scan_kernel(
    const float* __restrict__ em, const int* __restrict__ mask,
    const float* __restrict__ startT, const float* __restrict__ endT,
    const float* __restrict__ trans, float* __restrict__ out)
{
  const int lane = threadIdx.x;
  const int j = (lane < T) ? lane : (T - 1);   // idle lanes mirror state 16
  const int b = blockIdx.x;

  __shared__ float Ebuf[32];                   // 16B-aligned, padded

  // Linear-domain transition column for state j
  float w[T];
#pragma unroll
  for (int i = 0; i < T; ++i) w[i] = exp2f(trans[i * T + j] * LOG2E);

  const float* emb = em + (size_t)b * L * T;
  const int*   mkb = mask + (size_t)b * L;

  // init: alpha'_j = (start_j + em[b,0,j]) * log2e ; normalize so a[0]=0
  float v = (startT[j] + emb[j]) * LOG2E;
  float r = __shfl(v, 0, 64);
  float a = v - r;
  float C = r;

  // one-step prefetch of emissions + mask
  float em_nxt = emb[T + j];
  int   mt_nxt = mkb[1];

  for (int t = 1; t < L; ++t) {
    const float emt = em_nxt;
    const int   mt  = mt_nxt;
    const int   tn  = (t + 1 < L) ? (t + 1) : (L - 1);
    em_nxt = emb[(size_t)tn * T + j];
    mt_nxt = mkb[tn];

    const float E = exp2f(a);
    if (lane < T) Ebuf[lane] = E;
    __syncthreads();
    const float4 p0 = ((const float4*)Ebuf)[0];
    const float4 p1 = ((const float4*)Ebuf)[1];
    const float4 p2 = ((const float4*)Ebuf)[2];
    const float4 p3 = ((const float4*)Ebuf)[3];
    const float e16 = Ebuf[16];

    // S_j = sum_i E_i * W_ij  (4 independent FMA chains for ILP)
    float s0 = p0.x * w[0], s1 = p0.y * w[1], s2 = p0.z * w[2], s3 = p0.w * w[3];
    s0 = fmaf(p1.x, w[4],  s0); s1 = fmaf(p1.y, w[5],  s1);
    s2 = fmaf(p1.z, w[6],  s2); s3 = fmaf(p1.w, w[7],  s3);
    s0 = fmaf(p2.x, w[8],  s0); s1 = fmaf(p2.y, w[9],  s1);
    s2 = fmaf(p2.z, w[10], s2); s3 = fmaf(p2.w, w[11], s3);
    s0 = fmaf(p3.x, w[12], s0); s1 = fmaf(p3.y, w[13], s1);
    s2 = fmaf(p3.z, w[14], s2); s3 = fmaf(p3.w, w[15], s3);
    s0 = fmaf(e16, w[16], s0);
    const float S = (s0 + s1) + (s2 + s3);

    const float vnew = fmaf(emt, LOG2E, log2f(S));  // em' + log2(S) (rel. to C)
    r = __shfl(vnew, 0, 64);
    __syncthreads();                                // WAR guard on Ebuf
    if (mt != 0) { a = vnew - r; C += r; }          // masked commit
  }

  // denominator (natural log) = ln2 * (C + log2 sum_j 2^(a_j + end'_j))
  const float E2 = exp2f(a + endT[j] * LOG2E);
  if (lane < T) Ebuf[lane] = E2;
  __syncthreads();
  if (lane == 0) {
    float s = 0.f;
#pragma unroll
    for (int i = 0; i < T; ++i) s += Ebuf[i];
    const float den = (C + log2f(s)) * LN2;
    atomicAdd(out, den * (1.0f / B));
  }
}

// ---------------------------------------------------------------------------
// Numerator: gold-path score. One block per batch, strided gather + reduce.
// ---------------------------------------------------------------------------
__global__ __launch_bounds__(256) void crf_num_kernel(
    const float* __restrict__ em, const int* __restrict__ tags,
    const int* __restrict__ mask, const float* __restrict__ startT,
    const float* __restrict__ endT, const float* __restrict__ trans,
    float* __restrict__ out)
{
  const int b = blockIdx.x, tid = threadIdx.x;
  const float* emb = em + (size_t)b * L * T;
  const int* tg = tags + (size_t)b * L;
  const int* mk = mask + (size_t)b * L;

  float s = 0.f; int cnt = 0;
  for (int t = tid; t < L; t += 256) {
    const int tag = tg[t];
    const int m   = mk[t];
    cnt += (m != 0) ? 1 : 0;
    if (t == 0) {
      s += startT[tag] + emb[tag];                       // start + em[b,0,tag0]
    } else if (m != 0) {
      s += trans[tg[t - 1] * T + tag] + emb[(size_t)t * T + tag];
    }
  }

  __shared__ float fs[256];
  __shared__ int   cs[256];
  fs[tid] = s; cs[tid] = cnt;
  __syncthreads();
  for (int off = 128; off > 0; off >>= 1) {
    if (tid < off) { fs[tid] += fs[tid + off]; cs[tid] += cs[tid + off]; }
    __syncthreads();
  }
  if (tid == 0) {
    const int   last  = tg[cs[0] - 1];                   // tags[b, sum(mask)-1]
    const float total = fs[0] + endT[last];
    atomicAdd(out, -total * (1.0f / B));
  }
}

// ---------------------------------------------------------------------------
extern "C" void kernel_launch(void* const* d_in, const int* in_sizes, int n_in,
                              void* d_out, int out_size, void* d_ws, size_t ws_size,
                              hipStream_t stream)
{
  const float* em   = (const float*)d_in[0];
  const int*   tags = (const int*)d_in[1];
  const int*   mask = (const int*)d_in[2];
  const float* st   = (const float*)d_in[3];
  const float* en   = (const float*)d_in[4];
  const float* tr   = (const float*)d_in[5];
  float* out = (float*)d_out;

  // harness re-poisons d_out before every launch -> zero it ourselves
  hipMemsetAsync(out, 0, sizeof(float), stream);
  crf_num_kernel <<<B, 256, 0, stream>>>(em, tags, mask, st, en, tr, out);
  crf_scan_kernel<<<B,  64, 0, stream>>>(em, mask, st, en, tr, out);
}

// Round 4
// 260.606 us; speedup vs baseline: 2.0666x; 2.0666x over previous
//
#include <hip/hip_runtime.h>

static constexpr int B = 256, L = 2048, T = 17;
#define LOG2E 1.4426950408889634f
#define LN2   0.6931471805599453f

// broadcast lane i's float to all lanes via v_readlane (SGPR result)
__device__ __forceinline__ float rl(float v, int i) {
  return __int_as_float(__builtin_amdgcn_readlane(__float_as_int(v), i));
}

// ---------------------------------------------------------------------------
// Fused CRF kernel. One block per batch, 4 waves:
//   wave 0   : forward scan in LINEAR domain (denominator)
//   waves 1-3: gold-path numerator (runs concurrently on other SIMDs)
// Linear-domain scan: N'_j = (sum_i N_i * W_ij) * Em_j,
//   W_ij = 2^(trans_ij*log2e) (registers, lane j holds column j),
//   Em_j = 2^(em_j*log2e)    (prefetched, off critical path).
// Exact power-of-2 renorm every 8 steps: N *= 2^-e, C += e (e = lane0 exp).
// Cross-lane matvec via 17 v_readlane broadcasts (no LDS, no barriers).
// ---------------------------------------------------------------------------
__global__ __launch_bounds__(256) void crf_fused_kernel(
    const float* __restrict__ em, const int* __restrict__ tags,
    const int* __restrict__ mask, const float* __restrict__ startT,
    const float* __restrict__ endT, const float* __restrict__ trans,
    float* __restrict__ out)
{
  const int tid = threadIdx.x;
  const int b = blockIdx.x;

  __shared__ float s_den;
  __shared__ float red[256];
  __shared__ int   redc[256];

  const float* emb = em + (size_t)b * L * T;
  const int*   mkb = mask + (size_t)b * L;
  const int*   tg  = tags + (size_t)b * L;

  if (tid < 64) {
    // ------------------------- scan wave -------------------------
    const int lane = tid;
    const int jj = (lane < T) ? lane : (T - 1);   // idle lanes mirror state 16

    float w[T];
#pragma unroll
    for (int i = 0; i < T; ++i) w[i] = exp2f(trans[i * T + jj] * LOG2E);

    // init (t=0): alpha'_j = (start_j + em0_j)*log2e, renorm to lane 0
    float v0 = (startT[jj] + emb[jj]) * LOG2E;
    float C = rl(v0, 0);
    float N = exp2f(v0 - C);

    // one scan step: N = m ? (W^T N) * Em : N
    auto step = [&](float Em, int mt) {
      float s0 = rl(N, 0) * w[0];
      float s1 = rl(N, 1) * w[1];
      float s2 = rl(N, 2) * w[2];
      float s3 = rl(N, 3) * w[3];
      s0 = fmaf(rl(N, 4),  w[4],  s0);
      s1 = fmaf(rl(N, 5),  w[5],  s1);
      s2 = fmaf(rl(N, 6),  w[6],  s2);
      s3 = fmaf(rl(N, 7),  w[7],  s3);
      s0 = fmaf(rl(N, 8),  w[8],  s0);
      s1 = fmaf(rl(N, 9),  w[9],  s1);
      s2 = fmaf(rl(N, 10), w[10], s2);
      s3 = fmaf(rl(N, 11), w[11], s3);
      s0 = fmaf(rl(N, 12), w[12], s0);
      s1 = fmaf(rl(N, 13), w[13], s1);
      s2 = fmaf(rl(N, 14), w[14], s2);
      s3 = fmaf(rl(N, 15), w[15], s3);
      s0 = fmaf(rl(N, 16), w[16], s0);
      const float S = (s0 + s1) + (s2 + s3);
      const float Nn = S * Em;
      N = mt ? Nn : N;
    };

    // exact power-of-2 renormalization (keeps lane0 ~ [1,2))
    auto renorm = [&]() {
      const int bits = __builtin_amdgcn_readlane(__float_as_int(N), 0);
      const int Ee = (bits >> 23) & 0xff;
      N *= __int_as_float((254 - Ee) << 23);
      C += (float)(Ee - 127);
    };

    // prologue: steps t = 1..7 (unpipelined)
    for (int t = 1; t < 8; ++t) {
      const float e = emb[(size_t)t * T + jj];
      const int   m = mkb[t];
      step(exp2f(e * LOG2E), m);
    }
    renorm();

    // preload first 8-step block (t = 8..15)
    float emr[8];
#pragma unroll
    for (int k = 0; k < 8; ++k) emr[k] = emb[(size_t)(8 + k) * T + jj];
    int4 mA = *(const int4*)(mkb + 8);
    int4 mB = *(const int4*)(mkb + 12);

    // main loop: 255 blocks of 8 steps (t = 8..2047)
    for (int blk = 0; blk < 255; ++blk) {
      const int t0 = 8 + blk * 8;

      float Emc[8];
#pragma unroll
      for (int k = 0; k < 8; ++k) Emc[k] = exp2f(emr[k] * LOG2E);
      const int cm[8] = {mA.x, mA.y, mA.z, mA.w, mB.x, mB.y, mB.z, mB.w};

      if (blk < 254) {   // prefetch next block (has ~8 steps to land)
#pragma unroll
        for (int k = 0; k < 8; ++k)
          emr[k] = emb[(size_t)(t0 + 8 + k) * T + jj];
        mA = *(const int4*)(mkb + t0 + 8);
        mB = *(const int4*)(mkb + t0 + 12);
      }

#pragma unroll
      for (int k = 0; k < 8; ++k) step(Emc[k], cm[k]);
      renorm();
    }

    // denominator = ln2 * (C + log2 sum_j N_j * 2^(end'_j))
    const float E2 = N * exp2f(endT[jj] * LOG2E);
    float ssum = 0.f;
#pragma unroll
    for (int i = 0; i < T; ++i) ssum += rl(E2, i);
    const float den = (C + log2f(ssum)) * LN2;
    if (lane == 0) s_den = den;

  } else {
    // ---------------------- numerator waves ----------------------
    float s = 0.f; int cnt = 0;
    for (int t = tid - 64; t < L; t += 192) {
      const int tag = tg[t];
      const int m   = mkb[t];
      cnt += (m != 0) ? 1 : 0;
      if (t == 0) {
        s += startT[tag] + emb[tag];
      } else if (m != 0) {
        s += trans[tg[t - 1] * T + tag] + emb[(size_t)t * T + tag];
      }
    }
    red[tid] = s; redc[tid] = cnt;
  }

  __syncthreads();
  if (tid == 0) {
    float ns = 0.f; int cnt = 0;
    for (int i = 64; i < 256; ++i) { ns += red[i]; cnt += redc[i]; }
    const int   last = tg[cnt - 1];
    const float num  = ns + endT[last];
    atomicAdd(out, (s_den - num) * (1.0f / B));
  }
}

// ---------------------------------------------------------------------------
extern "C" void kernel_launch(void* const* d_in, const int* in_sizes, int n_in,
                              void* d_out, int out_size, void* d_ws, size_t ws_size,
                              hipStream_t stream)
{
  const float* em   = (const float*)d_in[0];
  const int*   tags = (const int*)d_in[1];
  const int*   mask = (const int*)d_in[2];
  const float* st   = (const float*)d_in[3];
  const float* en   = (const float*)d_in[4];
  const float* tr   = (const float*)d_in[5];
  float* out = (float*)d_out;

  hipMemsetAsync(out, 0, sizeof(float), stream);   // harness poisons d_out
  crf_fused_kernel<<<B, 256, 0, stream>>>(em, tags, mask, st, en, tr, out);
}